// Round 3
// baseline (15540.050 us; speedup 1.0000x reference)
//
#include <hip/hip_runtime.h>
#include <hip/hip_bf16.h>
#include <stdint.h>

#define LL 4096
#define EE 300
#define HH 512
#define G4H 2048
#define TT 11
#define TSTART 9
#define TSTOP 10
#define NEGINF -10000.0f

__device__ __forceinline__ float sigf(float x){
    x = fminf(fmaxf(x, -30.f), 30.f);
    return 1.0f / (1.0f + __expf(-x));
}
__device__ __forceinline__ float tanhfast(float x){
    x = fminf(fmaxf(x, -15.f), 15.f);
    float e = __expf(-2.0f * x);
    return (1.0f - e) / (1.0f + e);
}
__device__ __forceinline__ unsigned long long shfl_u64(unsigned long long v, int src){
    unsigned lo = (unsigned)v, hi = (unsigned)(v >> 32);
    lo = __shfl(lo, src, 64); hi = __shfl(hi, src, 64);
    return ((unsigned long long)hi << 32) | (unsigned long long)lo;
}
__device__ __forceinline__ unsigned long long lda(const unsigned long long* p){
    return __hip_atomic_load(p, __ATOMIC_RELAXED, __HIP_MEMORY_SCOPE_AGENT);
}

// ---------------- K0: zero the h-communication buffers (fresh tags each call)
__global__ void k0_zero(unsigned long long* __restrict__ comm){
    int i = blockIdx.x * blockDim.x + threadIdx.x;
    if (i < 2 * 2 * HH) comm[i] = 0ull;
}

// ---------------- K1: xg[dir][t][r] = emb[sent[t]] . w_ih[dir][r] + b_ih[r] + b_hh[r]
__global__ __launch_bounds__(256) void k1_xg(
    const int* __restrict__ sent, const float* __restrict__ emb,
    const float* __restrict__ wih_f, const float* __restrict__ bih_f, const float* __restrict__ bhh_f,
    const float* __restrict__ wih_b, const float* __restrict__ bih_b, const float* __restrict__ bhh_b,
    float* __restrict__ xg_f, float* __restrict__ xg_b)
{
    __shared__ float elds[32 * 304];
    int t0  = blockIdx.x * 32;
    int r0  = blockIdx.y * 256;
    int dir = blockIdx.z;
    const float* wih = dir ? wih_b : wih_f;
    const float* bih = dir ? bih_b : bih_f;
    const float* bhh = dir ? bhh_b : bhh_f;
    float* xg = dir ? xg_b : xg_f;

    for (int idx = threadIdx.x; idx < 32 * EE; idx += 256){
        int i = idx / EE, e = idx - i * EE;
        elds[i * 304 + e] = emb[(long)sent[t0 + i] * EE + e];
    }
    __syncthreads();

    int rA = r0 + (threadIdx.x & 127);
    int rB = rA + 128;
    int half = threadIdx.x >> 7;
    float accA[16], accB[16];
    #pragma unroll
    for (int i = 0; i < 16; i++){ accA[i] = 0.f; accB[i] = 0.f; }
    const float* wrowA = wih + (long)rA * EE;
    const float* wrowB = wih + (long)rB * EE;
    for (int e4 = 0; e4 < 75; e4++){
        float4 wa = *reinterpret_cast<const float4*>(wrowA + e4 * 4);
        float4 wb = *reinterpret_cast<const float4*>(wrowB + e4 * 4);
        #pragma unroll
        for (int i = 0; i < 16; i++){
            float4 ev = *reinterpret_cast<const float4*>(&elds[(half * 16 + i) * 304 + e4 * 4]);
            accA[i] += wa.x * ev.x + wa.y * ev.y + wa.z * ev.z + wa.w * ev.w;
            accB[i] += wb.x * ev.x + wb.y * ev.y + wb.z * ev.z + wb.w * ev.w;
        }
    }
    float bA = bih[rA] + bhh[rA];
    float bB = bih[rB] + bhh[rB];
    #pragma unroll
    for (int i = 0; i < 16; i++){
        int t = t0 + half * 16 + i;
        xg[(long)t * G4H + rA] = accA[i] + bA;
        xg[(long)t * G4H + rB] = accB[i] + bB;
    }
}

// ---------------- K2: persistent BiLSTM, fully wave-autonomous.
// 512 blocks x 64 threads. bid>>8 = dir, idx = bid&255 owns outputs {2idx, 2idx+1}.
// Lane l holds h columns {64k+l}; per step: batched poll of all 512 comm words
// (retry only stale), 64 reg-only FMA, paired-row butterfly reduce, lanes 0/1
// compute gates and publish. No LDS, no barriers, no wave0 serialization.
__global__ __launch_bounds__(64) void k2_lstm(
    const float* __restrict__ whh_f, const float* __restrict__ whh_b,
    const float* __restrict__ xg_f, const float* __restrict__ xg_b,
    float* __restrict__ hs_f, float* __restrict__ hs_b,
    unsigned long long* __restrict__ comm)
{
    int dir = blockIdx.x >> 8;
    int idx = blockIdx.x & 255;
    int l   = threadIdx.x;
    int jj  = l & 1;
    int jA  = idx * 2;                  // this wave's two outputs: jA, jA+1

    const float* whh = dir ? whh_b : whh_f;
    const float* xg  = dir ? xg_b  : xg_f;
    float* hs        = dir ? hs_b  : hs_f;
    unsigned long long* cm = comm + dir * 2 * HH;

    // wreg[r][k]: row r = gate(r>>1)*HH + jA + (r&1), column k*64+l
    float wreg[8][8];
    #pragma unroll
    for (int r = 0; r < 8; r++){
        const float* wp = whh + (size_t)((r >> 1) * HH + jA + (r & 1)) * HH + l;
        #pragma unroll
        for (int k = 0; k < 8; k++) wreg[r][k] = wp[k * 64];
    }

    float c = 0.f;

    for (int s = 0; s < LL; ++s){
        int t = dir ? (LL - 1 - s) : s;

        // prefetch xg for the gate stage (2 lanes, 4 gates each); in flight
        // during the poll
        float xgv0 = 0.f, xgv1 = 0.f, xgv2 = 0.f, xgv3 = 0.f;
        if (l < 2){
            const float* xp = xg + (size_t)t * G4H + jA + l;
            xgv0 = xp[0];
            xgv1 = xp[HH];
            xgv2 = xp[2 * HH];
            xgv3 = xp[3 * HH];
        }

        float h[8];
        if (s == 0){
            #pragma unroll
            for (int k = 0; k < 8; k++) h[k] = 0.f;
        } else {
            const unsigned long long* pw = cm + (s & 1) * HH + l;
            unsigned long long v[8];
            #pragma unroll
            for (int k = 0; k < 8; k++) v[k] = lda(pw + k * 64);
            unsigned want = (unsigned)s;
            for (;;){
                unsigned bad = 0;
                #pragma unroll
                for (int k = 0; k < 8; k++) bad |= ((unsigned)(v[k] >> 32)) ^ want;
                if (__all(bad == 0)) break;
                #pragma unroll
                for (int k = 0; k < 8; k++)
                    if ((unsigned)(v[k] >> 32) != want) v[k] = lda(pw + k * 64);
            }
            #pragma unroll
            for (int k = 0; k < 8; k++) h[k] = __uint_as_float((unsigned)v[k]);
        }

        // per-lane dot: acc[r] = sum_k wreg[r][k] * h[k]
        float acc[8];
        #pragma unroll
        for (int r = 0; r < 8; r++){
            float a0 = wreg[r][0] * h[0] + wreg[r][1] * h[1];
            float a1 = wreg[r][2] * h[2] + wreg[r][3] * h[3];
            float a2 = wreg[r][4] * h[4] + wreg[r][5] * h[5];
            float a3 = wreg[r][6] * h[6] + wreg[r][7] * h[7];
            acc[r] = (a0 + a1) + (a2 + a3);
        }

        // paired-row butterfly: after stage-1 mix, even lanes carry row 2g,
        // odd lanes row 2g+1; 5 more stages give full sums per parity.
        float pre[4];
        #pragma unroll
        for (int g = 0; g < 4; g++){
            float e = acc[2 * g]     + __shfl_xor(acc[2 * g],     1, 64);
            float o = acc[2 * g + 1] + __shfl_xor(acc[2 * g + 1], 1, 64);
            float z = jj ? o : e;
            #pragma unroll
            for (int off = 2; off < 64; off <<= 1) z += __shfl_xor(z, off, 64);
            pre[g] = z;
        }

        if (l < 2){
            float vi = pre[0] + xgv0;
            float vf = pre[1] + xgv1;
            float vg = pre[2] + xgv2;
            float vo = pre[3] + xgv3;
            c = sigf(vf) * c + sigf(vi) * tanhfast(vg);
            float hv = sigf(vo) * tanhfast(c);
            union { float f; unsigned u; } cv; cv.f = hv;
            unsigned long long pk = ((unsigned long long)(s + 1) << 32)
                                  | (unsigned long long)cv.u;
            __hip_atomic_store(cm + ((s + 1) & 1) * HH + (jA + l), pk,
                               __ATOMIC_RELAXED, __HIP_MEMORY_SCOPE_AGENT);
            hs[(size_t)t * HH + (jA + l)] = hv;
        }
        // Parity reuse safety: a producer publishes tag s+2 (overwriting tag-s
        // words) only after polling ALL tag-(s+1) words; each of those is
        // published by its owner only after that owner finished reading every
        // tag-s word. So no tag-s word is overwritten while still needed.
    }
}

// ---------------- K3: feats[t][n] = w_tag[n] . [hf[t], hb[t]] + b_tag[n]
__global__ __launch_bounds__(64) void k3_feats(
    const float* __restrict__ hs_f, const float* __restrict__ hs_b,
    const float* __restrict__ wtag, const float* __restrict__ btag,
    float* __restrict__ feats)
{
    int t = blockIdx.x;
    int lane = threadIdx.x;
    float hreg[16];
    #pragma unroll
    for (int q = 0; q < 16; q++){
        int k = q * 64 + lane;
        hreg[q] = (q < 8) ? hs_f[(long)t * HH + k] : hs_b[(long)t * HH + (k - HH)];
    }
    for (int n = 0; n < TT; n++){
        float a = 0.f;
        #pragma unroll
        for (int q = 0; q < 16; q++){
            a += wtag[n * 1024 + q * 64 + lane] * hreg[q];
        }
        #pragma unroll
        for (int off = 32; off; off >>= 1) a += __shfl_down(a, off, 64);
        if (lane == 0) feats[t * 12 + n] = a + btag[n];
    }
}

// ---------------- K4: Viterbi scan + backtrace on a single wave
__global__ __launch_bounds__(64) void k4_viterbi(
    const float* __restrict__ feats, const float* __restrict__ trans,
    float* __restrict__ out)
{
    __shared__ unsigned long long bplds[LL];
    int lane = threadIdx.x;
    float tr[TT];
    #pragma unroll
    for (int p = 0; p < TT; p++) tr[p] = (lane < TT) ? trans[lane * TT + p] : NEGINF;
    float fv = (lane == TSTART) ? 0.f : NEGINF;

    #define LDF(t) ((lane < TT) ? feats[(t) * 12 + lane] : 0.f)
    float f0 = LDF(0), f1 = LDF(1), f2 = LDF(2), f3 = LDF(3);

    for (int t = 0; t < LL; t += 4){
        #define VSTEP(FT, TNEXT, TCUR) { \
            float best = __shfl(fv, 0, 64) + tr[0]; int bp = 0; \
            _Pragma("unroll") \
            for (int p = 1; p < TT; p++){ \
                float sp = __shfl(fv, p, 64) + tr[p]; \
                if (sp > best){ best = sp; bp = p; } \
            } \
            unsigned lo = (lane < 8) ? ((unsigned)bp << (4 * lane)) : 0u; \
            unsigned hi = (lane >= 8 && lane < TT) ? ((unsigned)bp << (4 * (lane - 8))) : 0u; \
            _Pragma("unroll") \
            for (int off = 1; off < 16; off <<= 1){ \
                lo |= __shfl_xor(lo, off, 16); hi |= __shfl_xor(hi, off, 16); \
            } \
            if (lane == 0) bplds[TCUR] = (unsigned long long)lo | ((unsigned long long)hi << 32); \
            fv = best + FT; \
            FT = ((TNEXT) < LL) ? LDF(TNEXT) : 0.f; \
        }
        VSTEP(f0, t + 4, t)
        VSTEP(f1, t + 5, t + 1)
        VSTEP(f2, t + 6, t + 2)
        VSTEP(f3, t + 7, t + 3)
        #undef VSTEP
    }
    __syncthreads();

    float term = (lane < TT) ? (fv + trans[TSTOP * TT + lane]) : -3.0e38f;
    int idx = (lane < TT) ? lane : 63;
    #pragma unroll
    for (int off = 32; off; off >>= 1){
        float os = __shfl_down(term, off, 64);
        int   oi = __shfl_down(idx,  off, 64);
        if (os > term || (os == term && oi < idx)){ term = os; idx = oi; }
    }
    term = __shfl(term, 0, 64);
    idx  = __shfl(idx,  0, 64);
    if (lane == 0){
        out[0] = term;                  // path_score
        out[1 + (LL - 1)] = (float)idx; // path[L-1]
    }

    // backtrace: bp table register-resident (lane holds bplds[i*64+lane])
    unsigned long long bpr[64];
    #pragma unroll
    for (int i = 0; i < 64; i++) bpr[i] = bplds[i * 64 + lane];
    int tag = idx;
    #pragma unroll
    for (int i = 63; i >= 0; --i){
        for (int l2 = 63; l2 >= 0; --l2){
            int u = i * 64 + l2;
            if (u == 0) break;
            unsigned long long wv = shfl_u64(bpr[i], l2);
            tag = (int)((wv >> (4 * tag)) & 15ull);
            if (lane == 0) out[u] = (float)tag;  // out[1 + (u-1)]
        }
    }
}

__global__ void k_dbg(float* out, float v){ out[0] = v; }

extern "C" void kernel_launch(void* const* d_in, const int* in_sizes, int n_in,
                              void* d_out, int out_size, void* d_ws, size_t ws_size,
                              hipStream_t stream)
{
    const int*   sent  = (const int*)  d_in[0];
    const float* emb   = (const float*)d_in[1];
    const float* wih_f = (const float*)d_in[2];
    const float* whh_f = (const float*)d_in[3];
    const float* bih_f = (const float*)d_in[4];
    const float* bhh_f = (const float*)d_in[5];
    const float* wih_b = (const float*)d_in[6];
    const float* whh_b = (const float*)d_in[7];
    const float* bih_b = (const float*)d_in[8];
    const float* bhh_b = (const float*)d_in[9];
    const float* wtag  = (const float*)d_in[10];
    const float* btag  = (const float*)d_in[11];
    const float* trans = (const float*)d_in[12];
    float* out = (float*)d_out;

    char* ws = (char*)d_ws;
    size_t off = 0;
    float* xg_f = (float*)(ws + off); off += (size_t)LL * G4H * 4;
    float* xg_b = (float*)(ws + off); off += (size_t)LL * G4H * 4;
    float* hs_f = (float*)(ws + off); off += (size_t)LL * HH * 4;
    float* hs_b = (float*)(ws + off); off += (size_t)LL * HH * 4;
    float* feats= (float*)(ws + off); off += (size_t)LL * 12 * 4;
    unsigned long long* comm = (unsigned long long*)(ws + off); off += 2 * 2 * HH * 8;

    if (off > ws_size){
        k_dbg<<<1, 1, 0, stream>>>(out, (float)ws_size);
        return;
    }

    k0_zero<<<8, 256, 0, stream>>>(comm);
    k1_xg<<<dim3(128, 8, 2), 256, 0, stream>>>(sent, emb, wih_f, bih_f, bhh_f,
                                               wih_b, bih_b, bhh_b, xg_f, xg_b);
    k2_lstm<<<512, 64, 0, stream>>>(whh_f, whh_b, xg_f, xg_b, hs_f, hs_b, comm);
    k3_feats<<<LL, 64, 0, stream>>>(hs_f, hs_b, wtag, btag, feats);
    k4_viterbi<<<1, 64, 0, stream>>>(feats, trans, out);
}

// Round 4
// 12903.043 us; speedup vs baseline: 1.2044x; 1.2044x over previous
//
#include <hip/hip_runtime.h>
#include <hip/hip_bf16.h>
#include <stdint.h>

#define LL 4096
#define EE 300
#define HH 512
#define G4H 2048
#define TT 11
#define TSTART 9
#define TSTOP 10
#define NEGINF -10000.0f

__device__ __forceinline__ float sigf(float x){
    x = fminf(fmaxf(x, -30.f), 30.f);
    return 1.0f / (1.0f + __expf(-x));
}
__device__ __forceinline__ float tanhfast(float x){
    x = fminf(fmaxf(x, -15.f), 15.f);
    float e = __expf(-2.0f * x);
    return (1.0f - e) / (1.0f + e);
}
__device__ __forceinline__ unsigned long long shfl_u64(unsigned long long v, int src){
    unsigned lo = (unsigned)v, hi = (unsigned)(v >> 32);
    lo = __shfl(lo, src, 64); hi = __shfl(hi, src, 64);
    return ((unsigned long long)hi << 32) | (unsigned long long)lo;
}
__device__ __forceinline__ unsigned long long lda(const unsigned long long* p){
    return __hip_atomic_load(p, __ATOMIC_RELAXED, __HIP_MEMORY_SCOPE_AGENT);
}

// ---------------- K0: zero the h-communication buffers (fresh tags each call)
__global__ void k0_zero(unsigned long long* __restrict__ comm){
    int i = blockIdx.x * blockDim.x + threadIdx.x;
    if (i < 2 * 2 * HH) comm[i] = 0ull;
}

// ---------------- K1: xg[dir][t][r] = emb[sent[t]] . w_ih[dir][r] + b_ih[r] + b_hh[r]
__global__ __launch_bounds__(256) void k1_xg(
    const int* __restrict__ sent, const float* __restrict__ emb,
    const float* __restrict__ wih_f, const float* __restrict__ bih_f, const float* __restrict__ bhh_f,
    const float* __restrict__ wih_b, const float* __restrict__ bih_b, const float* __restrict__ bhh_b,
    float* __restrict__ xg_f, float* __restrict__ xg_b)
{
    __shared__ float elds[32 * 304];
    int t0  = blockIdx.x * 32;
    int r0  = blockIdx.y * 256;
    int dir = blockIdx.z;
    const float* wih = dir ? wih_b : wih_f;
    const float* bih = dir ? bih_b : bih_f;
    const float* bhh = dir ? bhh_b : bhh_f;
    float* xg = dir ? xg_b : xg_f;

    for (int idx = threadIdx.x; idx < 32 * EE; idx += 256){
        int i = idx / EE, e = idx - i * EE;
        elds[i * 304 + e] = emb[(long)sent[t0 + i] * EE + e];
    }
    __syncthreads();

    int rA = r0 + (threadIdx.x & 127);
    int rB = rA + 128;
    int half = threadIdx.x >> 7;
    float accA[16], accB[16];
    #pragma unroll
    for (int i = 0; i < 16; i++){ accA[i] = 0.f; accB[i] = 0.f; }
    const float* wrowA = wih + (long)rA * EE;
    const float* wrowB = wih + (long)rB * EE;
    for (int e4 = 0; e4 < 75; e4++){
        float4 wa = *reinterpret_cast<const float4*>(wrowA + e4 * 4);
        float4 wb = *reinterpret_cast<const float4*>(wrowB + e4 * 4);
        #pragma unroll
        for (int i = 0; i < 16; i++){
            float4 ev = *reinterpret_cast<const float4*>(&elds[(half * 16 + i) * 304 + e4 * 4]);
            accA[i] += wa.x * ev.x + wa.y * ev.y + wa.z * ev.z + wa.w * ev.w;
            accB[i] += wb.x * ev.x + wb.y * ev.y + wb.z * ev.z + wb.w * ev.w;
        }
    }
    float bA = bih[rA] + bhh[rA];
    float bB = bih[rB] + bhh[rB];
    #pragma unroll
    for (int i = 0; i < 16; i++){
        int t = t0 + half * 16 + i;
        xg[(long)t * G4H + rA] = accA[i] + bA;
        xg[(long)t * G4H + rB] = accB[i] + bB;
    }
}

// ---------------- K2: persistent BiLSTM — R1 poll distribution + wave-autonomous compute.
// 64 blocks x 512 thr. bid>>5 = dir, b = bid&31 owns j [16b,16b+16). Wave w owns
// j {16b+2w, 16b+2w+1} end-to-end. Per step: thread tid polls comm word tid (one
// word each, minimal fabric load), stages to LDS, one barrier; each wave loads
// full h to regs (8 ds_read_b32), 64 reg-FMA, in-wave butterfly, lanes 0/1 do
// gates and publish. No wave0 serialization, no second barrier.
__global__ __launch_bounds__(512) void k2_lstm(
    const float* __restrict__ whh_f, const float* __restrict__ whh_b,
    const float* __restrict__ xg_f, const float* __restrict__ xg_b,
    float* __restrict__ hs_f, float* __restrict__ hs_b,
    unsigned long long* __restrict__ comm)
{
    int dir = blockIdx.x >> 5;
    int b   = blockIdx.x & 31;
    int j0  = b * 16;
    int tid = threadIdx.x;
    int w   = tid >> 6;
    int l   = tid & 63;
    int jj  = l & 1;
    int jA  = j0 + 2 * w;             // wave's two outputs: jA, jA+1

    const float* whh = dir ? whh_b : whh_f;
    const float* xg  = dir ? xg_b  : xg_f;
    float* hs        = dir ? hs_b  : hs_f;
    unsigned long long* cm = comm + dir * 2 * HH;

    // wreg[r][k]: row (g = r>>1)*HH + jA + (r&1), column k*64 + l
    float wreg[8][8];
    #pragma unroll
    for (int r = 0; r < 8; r++){
        const float* wp = whh + (size_t)((r >> 1) * HH + jA + (r & 1)) * HH + l;
        #pragma unroll
        for (int k = 0; k < 8; k++) wreg[r][k] = wp[k * 64];
    }

    __shared__ float hlds[2][HH];
    float c = 0.f;

    for (int s = 0; s < LL; ++s){
        int t = dir ? (LL - 1 - s) : s;

        // xg prefetch for the gate tail (lanes 0,1 of every wave); overlaps poll
        float xgv0 = 0.f, xgv1 = 0.f, xgv2 = 0.f, xgv3 = 0.f;
        if (l < 2){
            const float* xp = xg + (size_t)t * G4H + jA + l;
            xgv0 = xp[0];
            xgv1 = xp[HH];
            xgv2 = xp[2 * HH];
            xgv3 = xp[3 * HH];
        }

        if (s > 0){
            const unsigned long long* pw = cm + (s & 1) * HH + tid;
            unsigned long long v = lda(pw);
            unsigned want = (unsigned)s;
            while (!__all((unsigned)(v >> 32) == want)){
                if ((unsigned)(v >> 32) != want) v = lda(pw);
            }
            hlds[s & 1][tid] = __uint_as_float((unsigned)v);
        }
        __syncthreads();
        // One barrier/step is safe: a wave reaches the write of hlds[(s+1)&1]
        // only after its poll(s+1) succeeds, which requires every wave of this
        // block to have published step s -- i.e. to have already read hlds[s&1].

        // full h into registers: h[k] = h[k*64 + l]
        float h[8];
        if (s == 0){
            #pragma unroll
            for (int k = 0; k < 8; k++) h[k] = 0.f;
        } else {
            #pragma unroll
            for (int k = 0; k < 8; k++) h[k] = hlds[s & 1][k * 64 + l];
        }

        // per-lane dot: acc[r] = sum_k wreg[r][k] * h[k]
        float acc[8];
        #pragma unroll
        for (int r = 0; r < 8; r++){
            float a0 = wreg[r][0] * h[0] + wreg[r][1] * h[1];
            float a1 = wreg[r][2] * h[2] + wreg[r][3] * h[3];
            float a2 = wreg[r][4] * h[4] + wreg[r][5] * h[5];
            float a3 = wreg[r][6] * h[6] + wreg[r][7] * h[7];
            acc[r] = (a0 + a1) + (a2 + a3);
        }

        // paired-row butterfly: even lanes end with row 2g, odd lanes row 2g+1
        float pre[4];
        #pragma unroll
        for (int g = 0; g < 4; g++){
            float e = acc[2 * g]     + __shfl_xor(acc[2 * g],     1, 64);
            float o = acc[2 * g + 1] + __shfl_xor(acc[2 * g + 1], 1, 64);
            float z = jj ? o : e;
            #pragma unroll
            for (int off = 2; off < 64; off <<= 1) z += __shfl_xor(z, off, 64);
            pre[g] = z;
        }

        if (l < 2){
            float vi = pre[0] + xgv0;
            float vf = pre[1] + xgv1;
            float vg = pre[2] + xgv2;
            float vo = pre[3] + xgv3;
            c = sigf(vf) * c + sigf(vi) * tanhfast(vg);
            float hv = sigf(vo) * tanhfast(c);
            union { float f; unsigned u; } cv; cv.f = hv;
            unsigned long long pk = ((unsigned long long)(s + 1) << 32)
                                  | (unsigned long long)cv.u;
            __hip_atomic_store(cm + ((s + 1) & 1) * HH + (jA + l), pk,
                               __ATOMIC_RELAXED, __HIP_MEMORY_SCOPE_AGENT);
            hs[(size_t)t * HH + (jA + l)] = hv;
        }
    }
}

// ---------------- K3: feats[t][n] = w_tag[n] . [hf[t], hb[t]] + b_tag[n]
__global__ __launch_bounds__(64) void k3_feats(
    const float* __restrict__ hs_f, const float* __restrict__ hs_b,
    const float* __restrict__ wtag, const float* __restrict__ btag,
    float* __restrict__ feats)
{
    int t = blockIdx.x;
    int lane = threadIdx.x;
    float hreg[16];
    #pragma unroll
    for (int q = 0; q < 16; q++){
        int k = q * 64 + lane;
        hreg[q] = (q < 8) ? hs_f[(long)t * HH + k] : hs_b[(long)t * HH + (k - HH)];
    }
    for (int n = 0; n < TT; n++){
        float a = 0.f;
        #pragma unroll
        for (int q = 0; q < 16; q++){
            a += wtag[n * 1024 + q * 64 + lane] * hreg[q];
        }
        #pragma unroll
        for (int off = 32; off; off >>= 1) a += __shfl_down(a, off, 64);
        if (lane == 0) feats[t * 12 + n] = a + btag[n];
    }
}

// ---------------- K4: Viterbi scan + backtrace on a single wave
__global__ __launch_bounds__(64) void k4_viterbi(
    const float* __restrict__ feats, const float* __restrict__ trans,
    float* __restrict__ out)
{
    __shared__ unsigned long long bplds[LL];
    int lane = threadIdx.x;
    float tr[TT];
    #pragma unroll
    for (int p = 0; p < TT; p++) tr[p] = (lane < TT) ? trans[lane * TT + p] : NEGINF;
    float fv = (lane == TSTART) ? 0.f : NEGINF;

    #define LDF(t) ((lane < TT) ? feats[(t) * 12 + lane] : 0.f)
    float f0 = LDF(0), f1 = LDF(1), f2 = LDF(2), f3 = LDF(3);

    for (int t = 0; t < LL; t += 4){
        #define VSTEP(FT, TNEXT, TCUR) { \
            float best = __shfl(fv, 0, 64) + tr[0]; int bp = 0; \
            _Pragma("unroll") \
            for (int p = 1; p < TT; p++){ \
                float sp = __shfl(fv, p, 64) + tr[p]; \
                if (sp > best){ best = sp; bp = p; } \
            } \
            unsigned lo = (lane < 8) ? ((unsigned)bp << (4 * lane)) : 0u; \
            unsigned hi = (lane >= 8 && lane < TT) ? ((unsigned)bp << (4 * (lane - 8))) : 0u; \
            _Pragma("unroll") \
            for (int off = 1; off < 16; off <<= 1){ \
                lo |= __shfl_xor(lo, off, 16); hi |= __shfl_xor(hi, off, 16); \
            } \
            if (lane == 0) bplds[TCUR] = (unsigned long long)lo | ((unsigned long long)hi << 32); \
            fv = best + FT; \
            FT = ((TNEXT) < LL) ? LDF(TNEXT) : 0.f; \
        }
        VSTEP(f0, t + 4, t)
        VSTEP(f1, t + 5, t + 1)
        VSTEP(f2, t + 6, t + 2)
        VSTEP(f3, t + 7, t + 3)
        #undef VSTEP
    }
    __syncthreads();

    float term = (lane < TT) ? (fv + trans[TSTOP * TT + lane]) : -3.0e38f;
    int idx = (lane < TT) ? lane : 63;
    #pragma unroll
    for (int off = 32; off; off >>= 1){
        float os = __shfl_down(term, off, 64);
        int   oi = __shfl_down(idx,  off, 64);
        if (os > term || (os == term && oi < idx)){ term = os; idx = oi; }
    }
    term = __shfl(term, 0, 64);
    idx  = __shfl(idx,  0, 64);
    if (lane == 0){
        out[0] = term;                  // path_score
        out[1 + (LL - 1)] = (float)idx; // path[L-1]
    }

    // backtrace: bp table register-resident (lane holds bplds[i*64+lane])
    unsigned long long bpr[64];
    #pragma unroll
    for (int i = 0; i < 64; i++) bpr[i] = bplds[i * 64 + lane];
    int tag = idx;
    #pragma unroll
    for (int i = 63; i >= 0; --i){
        for (int l2 = 63; l2 >= 0; --l2){
            int u = i * 64 + l2;
            if (u == 0) break;
            unsigned long long wv = shfl_u64(bpr[i], l2);
            tag = (int)((wv >> (4 * tag)) & 15ull);
            if (lane == 0) out[u] = (float)tag;  // out[1 + (u-1)]
        }
    }
}

__global__ void k_dbg(float* out, float v){ out[0] = v; }

extern "C" void kernel_launch(void* const* d_in, const int* in_sizes, int n_in,
                              void* d_out, int out_size, void* d_ws, size_t ws_size,
                              hipStream_t stream)
{
    const int*   sent  = (const int*)  d_in[0];
    const float* emb   = (const float*)d_in[1];
    const float* wih_f = (const float*)d_in[2];
    const float* whh_f = (const float*)d_in[3];
    const float* bih_f = (const float*)d_in[4];
    const float* bhh_f = (const float*)d_in[5];
    const float* wih_b = (const float*)d_in[6];
    const float* whh_b = (const float*)d_in[7];
    const float* bih_b = (const float*)d_in[8];
    const float* bhh_b = (const float*)d_in[9];
    const float* wtag  = (const float*)d_in[10];
    const float* btag  = (const float*)d_in[11];
    const float* trans = (const float*)d_in[12];
    float* out = (float*)d_out;

    char* ws = (char*)d_ws;
    size_t off = 0;
    float* xg_f = (float*)(ws + off); off += (size_t)LL * G4H * 4;
    float* xg_b = (float*)(ws + off); off += (size_t)LL * G4H * 4;
    float* hs_f = (float*)(ws + off); off += (size_t)LL * HH * 4;
    float* hs_b = (float*)(ws + off); off += (size_t)LL * HH * 4;
    float* feats= (float*)(ws + off); off += (size_t)LL * 12 * 4;
    unsigned long long* comm = (unsigned long long*)(ws + off); off += 2 * 2 * HH * 8;

    if (off > ws_size){
        k_dbg<<<1, 1, 0, stream>>>(out, (float)ws_size);
        return;
    }

    k0_zero<<<8, 256, 0, stream>>>(comm);
    k1_xg<<<dim3(128, 8, 2), 256, 0, stream>>>(sent, emb, wih_f, bih_f, bhh_f,
                                               wih_b, bih_b, bhh_b, xg_f, xg_b);
    k2_lstm<<<64, 512, 0, stream>>>(whh_f, whh_b, xg_f, xg_b, hs_f, hs_b, comm);
    k3_feats<<<LL, 64, 0, stream>>>(hs_f, hs_b, wtag, btag, feats);
    k4_viterbi<<<1, 64, 0, stream>>>(feats, trans, out);
}